// Round 16
// baseline (37757.260 us; speedup 1.0000x reference)
//
#include <hip/hip_runtime.h>
#include <hip/hip_bf16.h>

// R16: THE FIX — output buffer is FP32 (not bf16). The readback branches on
// out_dtype_str; my bf16 assumption (from the test label) was wrong since R0.
// Proof: R9 wrote bf16 100.0 into bytes 0-1 -> low half of fp32[0] -> denormal
// ~0 -> absmax = max|ref| = 1.34375 exactly as observed. Under fp32-output,
// every one of the 15 rounds' absmax values is explained, including the
// bit-stable 2.019531 for three independent faithful pipelines (comparison
// paired ref[i] with my bf16 element 2i+1 -> decorrelation artifact).
// Pipeline = R7 faithful fp32 (proven), with fp32 stores; hs fp32 if ws
// allows, else bf16.

typedef __bf16 bf16_t;

#define EMB 256
#define TSTEPS 128
#define OUTD 64

#define HS_OFF 0u
#define H0_F32_OFF 67108864u   // when hs is fp32: hs = 64 MB, h0 after
#define H0_B16_OFF 33554432u   // when hs is bf16: hs = 32 MB, h0 after
#define WS_F32_NEEDED (67108864u + 524288u)

// ---------------------------------------------------------------------------
__global__ __launch_bounds__(256) void emb_kernel(
    const float* __restrict__ z_t, const float* __restrict__ z_g,
    const float* __restrict__ w_emb, float* __restrict__ h0)
{
  __shared__ float zrow[128];
  const int bw = blockIdx.x, tid = threadIdx.x;
  if (tid < 128)
    zrow[tid] = (tid < 64) ? z_t[bw * 64 + tid] : z_g[(bw >> 4) * 64 + (tid - 64)];
  __syncthreads();
  const float4* wp = reinterpret_cast<const float4*>(w_emb + (size_t)tid * 128);
  float s = 0.f;
#pragma unroll
  for (int k4 = 0; k4 < 32; ++k4) {
    const float4 w = wp[k4];
    s += zrow[k4 * 4 + 0] * w.x + zrow[k4 * 4 + 1] * w.y
       + zrow[k4 * 4 + 2] * w.z + zrow[k4 * 4 + 3] * w.w;
  }
  h0[(size_t)bw * 256 + tid] = s;
}

// ---------------------------------------------------------------------------
// GRU fp32: 128 WGs x 256 thr, 4 rows/WG. Post-update emission, hs row=bw*128+t.
// ---------------------------------------------------------------------------
template <typename ST>
__global__ __launch_bounds__(256) void gru_fp32(
    const float* __restrict__ h0, const float* __restrict__ whh,
    const float* __restrict__ bih, const float* __restrict__ bhh,
    ST* __restrict__ hs)
{
  __shared__ __align__(16) float h[4][256];
  __shared__ __align__(16) float gh[4][768];
  const int tid = threadIdx.x;
  const int bw0 = blockIdx.x * 4;

#pragma unroll
  for (int r = 0; r < 4; ++r) h[r][tid] = h0[(size_t)(bw0 + r) * 256 + tid];
  const float br  = bih[tid]       + bhh[tid];
  const float bz  = bih[256 + tid] + bhh[256 + tid];
  const float bin = bih[512 + tid];
  const float bhn = bhh[512 + tid];
  __syncthreads();

#pragma unroll 1
  for (int t = 0; t < TSTEPS; ++t) {
#pragma unroll 1
    for (int g = 0; g < 3; ++g) {
      const int j = g * 256 + tid;
      const float4* wr = reinterpret_cast<const float4*>(whh + (size_t)j * 256);
      float s0 = 0.f, s1 = 0.f, s2 = 0.f, s3 = 0.f;
#pragma unroll 4
      for (int k4 = 0; k4 < 64; ++k4) {
        const float4 w = wr[k4];
        const float4 a0 = *reinterpret_cast<const float4*>(&h[0][k4 * 4]);
        const float4 a1 = *reinterpret_cast<const float4*>(&h[1][k4 * 4]);
        const float4 a2 = *reinterpret_cast<const float4*>(&h[2][k4 * 4]);
        const float4 a3 = *reinterpret_cast<const float4*>(&h[3][k4 * 4]);
        s0 += a0.x * w.x + a0.y * w.y + a0.z * w.z + a0.w * w.w;
        s1 += a1.x * w.x + a1.y * w.y + a1.z * w.z + a1.w * w.w;
        s2 += a2.x * w.x + a2.y * w.y + a2.z * w.z + a2.w * w.w;
        s3 += a3.x * w.x + a3.y * w.y + a3.z * w.z + a3.w * w.w;
      }
      gh[0][j] = s0; gh[1][j] = s1; gh[2][j] = s2; gh[3][j] = s3;
    }
    __syncthreads();

#pragma unroll
    for (int r = 0; r < 4; ++r) {
      const float gr = gh[r][tid]       + br;
      const float gz = gh[r][256 + tid] + bz;
      const float gn = gh[r][512 + tid] + bhn;
      const float rr = 1.f / (1.f + expf(-gr));
      const float zz = 1.f / (1.f + expf(-gz));
      const float nn = tanhf(bin + rr * gn);
      const float hn = (1.f - zz) * nn + zz * h[r][tid];
      h[r][tid] = hn;
      hs[((size_t)(bw0 + r) * TSTEPS + t) * EMB + tid] = (ST)hn;
    }
    __syncthreads();
  }
}

// ---------------------------------------------------------------------------
// MLP fp32: 4096 WGs x 256 thr, 16 rows/WG. FP32 output stores.
// ---------------------------------------------------------------------------
template <typename ST>
__global__ __launch_bounds__(256) void mlp_fp32(
    const ST* __restrict__ hs,
    const float* __restrict__ w1, const float* __restrict__ b1,
    const float* __restrict__ w2, const float* __restrict__ b2,
    const float* __restrict__ w3, const float* __restrict__ b3,
    const float* __restrict__ muw, const float* __restrict__ mub,
    float* __restrict__ out)
{
  __shared__ __align__(16) float A[16][512];
  const int tid = threadIdx.x;
  const size_t r0 = (size_t)blockIdx.x * 16;

  for (int i = tid; i < 16 * 256; i += 256) {
    const int rr = i >> 8, k = i & 255;
    A[rr][k] = (float)hs[(r0 + rr) * EMB + k];
  }
  __syncthreads();

  { // layer 1: 256 -> 512
    float acc[32];
#pragma unroll 1
    for (int i = 0; i < 32; ++i) {
      const int d = tid + 256 * i, rr = d >> 9, n = d & 511;
      const float4* wr = reinterpret_cast<const float4*>(w1 + (size_t)n * 256);
      const float4* ar = reinterpret_cast<const float4*>(&A[rr][0]);
      float s = b1[n];
#pragma unroll 4
      for (int k4 = 0; k4 < 64; ++k4) {
        const float4 w = wr[k4], a = ar[k4];
        s += a.x * w.x + a.y * w.y + a.z * w.z + a.w * w.w;
      }
      acc[i] = (s > 0.f) ? s : expm1f(s);
    }
    __syncthreads();
#pragma unroll
    for (int i = 0; i < 32; ++i) { const int d = tid + 256 * i; A[d >> 9][d & 511] = acc[i]; }
    __syncthreads();
  }

  const float* W[2]  = { w2, w3 };
  const float* Bv[2] = { b2, b3 };
#pragma unroll 1
  for (int L = 0; L < 2; ++L) { // layers 2,3: 512 -> 512
    float acc[32];
#pragma unroll 1
    for (int i = 0; i < 32; ++i) {
      const int d = tid + 256 * i, rr = d >> 9, n = d & 511;
      const float4* wr = reinterpret_cast<const float4*>(W[L] + (size_t)n * 512);
      const float4* ar = reinterpret_cast<const float4*>(&A[rr][0]);
      float s = Bv[L][n];
#pragma unroll 4
      for (int k4 = 0; k4 < 128; ++k4) {
        const float4 w = wr[k4], a = ar[k4];
        s += a.x * w.x + a.y * w.y + a.z * w.z + a.w * w.w;
      }
      acc[i] = (s > 0.f) ? s : expm1f(s);
    }
    __syncthreads();
#pragma unroll
    for (int i = 0; i < 32; ++i) { const int d = tid + 256 * i; A[d >> 9][d & 511] = acc[i]; }
    __syncthreads();
  }

  // mu head: 512 -> 64, FP32 stores
#pragma unroll 1
  for (int i = 0; i < 4; ++i) {
    const int d = tid + 256 * i, rr = d >> 6, o = d & 63;
    const float4* wr = reinterpret_cast<const float4*>(muw + (size_t)o * 512);
    const float4* ar = reinterpret_cast<const float4*>(&A[rr][0]);
    float s = mub[o];
#pragma unroll 4
    for (int k4 = 0; k4 < 128; ++k4) {
      const float4 w = wr[k4], a = ar[k4];
      s += a.x * w.x + a.y * w.y + a.z * w.z + a.w * w.w;
    }
    out[(r0 + rr) * OUTD + o] = s;   // FP32 output
  }
}

// ---------------------------------------------------------------------------
extern "C" void kernel_launch(void* const* d_in, const int* in_sizes, int n_in,
                              void* d_out, int out_size, void* d_ws, size_t ws_size,
                              hipStream_t stream) {
  char* ws = (char*)d_ws;
  float* out = (float*)d_out;

  const float* zt   = (const float*)d_in[0];
  const float* zg   = (const float*)d_in[1];
  const float* wemb = (const float*)d_in[2];
  const float* whh  = (const float*)d_in[3];
  const float* bih  = (const float*)d_in[4];
  const float* bhh  = (const float*)d_in[5];

  if (ws_size >= (size_t)WS_F32_NEEDED) {
    float* hs = (float*)(ws + HS_OFF);
    float* h0 = (float*)(ws + H0_F32_OFF);
    emb_kernel<<<512, 256, 0, stream>>>(zt, zg, wemb, h0);
    gru_fp32<float><<<128, 256, 0, stream>>>(h0, whh, bih, bhh, hs);
    mlp_fp32<float><<<4096, 256, 0, stream>>>(hs,
        (const float*)d_in[6],  (const float*)d_in[7],
        (const float*)d_in[8],  (const float*)d_in[9],
        (const float*)d_in[10], (const float*)d_in[11],
        (const float*)d_in[12], (const float*)d_in[13], out);
  } else {
    bf16_t* hs = (bf16_t*)(ws + HS_OFF);
    float*  h0 = (float*)(ws + H0_B16_OFF);
    emb_kernel<<<512, 256, 0, stream>>>(zt, zg, wemb, h0);
    gru_fp32<bf16_t><<<128, 256, 0, stream>>>(h0, whh, bih, bhh, hs);
    mlp_fp32<bf16_t><<<4096, 256, 0, stream>>>(hs,
        (const float*)d_in[6],  (const float*)d_in[7],
        (const float*)d_in[8],  (const float*)d_in[9],
        (const float*)d_in[10], (const float*)d_in[11],
        (const float*)d_in[12], (const float*)d_in[13], out);
  }
}

// Round 17
// 681.623 us; speedup vs baseline: 55.3932x; 55.3932x over previous
//
#include <hip/hip_runtime.h>
#include <hip/hip_bf16.h>

// R17: optimization round. Correctness established (R16, fp32 out, bf16 hs =
// absmax 0.00195). This is the R4-R6 internally-verified bf16 MFMA pipeline:
// convert weights fp32->bf16, register-resident W_hh GRU (32 WGs x 8 waves),
// fused 4-layer MFMA MLP (1024 WGs), fp32 output stores.

typedef __bf16 bf16_t;
typedef __bf16 bf16x8 __attribute__((ext_vector_type(8)));
typedef float f32x4 __attribute__((ext_vector_type(4)));

#define MFMA16(a, b, c) __builtin_amdgcn_mfma_f32_16x16x32_bf16(a, b, c, 0, 0, 0)

#define EMB 256
#define TSTEPS 128
#define OUTD 64

// ws layout (bytes): total 35,848,192 < proven 36.1 MB
#define HS_OFF   0u           // bf16 65536x256 = 33,554,432
#define H0_OFF   33554432u    // f32 512x256   = 524,288
#define WHH_OFF  34078720u    // bf16 768x256  = 393,216
#define W1_OFF   34471936u    // bf16 512x256  = 262,144
#define W2_OFF   34734080u    // bf16 512x512  = 524,288
#define W3_OFF   35258368u    // bf16 512x512  = 524,288
#define MUW_OFF  35782656u    // bf16 64x512   = 65,536

// ---------------------------------------------------------------------------
__global__ __launch_bounds__(256) void convert_kernel(
    const float* __restrict__ whh, const float* __restrict__ w1,
    const float* __restrict__ w2, const float* __restrict__ w3,
    const float* __restrict__ muw, char* __restrict__ ws)
{
  const int g = blockIdx.x * 256 + threadIdx.x;
  const int G = gridDim.x * 256;
  bf16_t* d;
  d = (bf16_t*)(ws + WHH_OFF); for (int i = g; i < 196608; i += G) d[i] = (bf16_t)whh[i];
  d = (bf16_t*)(ws + W1_OFF);  for (int i = g; i < 131072; i += G) d[i] = (bf16_t)w1[i];
  d = (bf16_t*)(ws + W2_OFF);  for (int i = g; i < 262144; i += G) d[i] = (bf16_t)w2[i];
  d = (bf16_t*)(ws + W3_OFF);  for (int i = g; i < 262144; i += G) d[i] = (bf16_t)w3[i];
  d = (bf16_t*)(ws + MUW_OFF); for (int i = g; i < 32768;  i += G) d[i] = (bf16_t)muw[i];
}

// ---------------------------------------------------------------------------
__global__ __launch_bounds__(256) void emb_kernel(
    const float* __restrict__ z_t, const float* __restrict__ z_g,
    const float* __restrict__ w_emb, float* __restrict__ h0)
{
  __shared__ float zrow[128];
  const int bw = blockIdx.x, tid = threadIdx.x;
  if (tid < 128)
    zrow[tid] = (tid < 64) ? z_t[bw * 64 + tid] : z_g[(bw >> 4) * 64 + (tid - 64)];
  __syncthreads();
  const float4* wp = reinterpret_cast<const float4*>(w_emb + (size_t)tid * 128);
  float s = 0.f;
#pragma unroll
  for (int k4 = 0; k4 < 32; ++k4) {
    const float4 w = wp[k4];
    s += zrow[k4 * 4 + 0] * w.x + zrow[k4 * 4 + 1] * w.y
       + zrow[k4 * 4 + 2] * w.z + zrow[k4 * 4 + 3] * w.w;
  }
  h0[(size_t)bw * 256 + tid] = s;
}

// ---------------------------------------------------------------------------
// GRU: 32 WGs x 512 thr (8 waves), 16 rows/WG. W_hh bf16 register-resident as
// MFMA B-fragments (wave wv owns gh cols [wv*96,+96) as 6 col-tiles).
// h fp32 master in gate-thread registers; bf16 copy in LDS for MFMA A-reads.
// Verified vs VALU replica (R6). LDS 61,952 B.
// ---------------------------------------------------------------------------
__global__ __launch_bounds__(512) void gru_kernel(
    const float* __restrict__ h0, const bf16_t* __restrict__ w_hh,
    const float* __restrict__ b_ih, const float* __restrict__ b_hh,
    bf16_t* __restrict__ hs)
{
  __shared__ __align__(16) float  gh[16][772];
  __shared__ __align__(16) bf16_t h16[16][264];
  __shared__ float bsum_r[256], bsum_z[256], bin_s[256], bhhn_s[256];

  const int tid  = threadIdx.x;
  const int wv   = tid >> 6;
  const int lane = tid & 63;
  const int l15  = lane & 15;
  const int quad = lane >> 4;
  const int bw0  = blockIdx.x * 16;
  const int gm   = tid >> 5;       // gate row 0..15
  const int gl   = tid & 31;       // gate col lane; owns cols gl + 32j

  // register-resident W_hh: lane holds W[n=wv*96+ct*16+l15][k=quad*8+j]
  bf16x8 wfrag[6][8];
#pragma unroll
  for (int ct = 0; ct < 6; ++ct) {
    const int n = wv * 96 + ct * 16 + l15;
#pragma unroll
    for (int kk = 0; kk < 8; ++kk)
      wfrag[ct][kk] = *reinterpret_cast<const bf16x8*>(w_hh + n * 256 + kk * 32 + quad * 8);
  }

  for (int i = tid; i < 256; i += 512) {
    bsum_r[i] = b_ih[i]       + b_hh[i];
    bsum_z[i] = b_ih[256 + i] + b_hh[256 + i];
    bin_s[i]  = b_ih[512 + i];
    bhhn_s[i] = b_hh[512 + i];
  }

  float hreg[8];
#pragma unroll
  for (int j = 0; j < 8; ++j) {
    const int c = gl + 32 * j;
    hreg[j] = h0[(size_t)(bw0 + gm) * 256 + c];
    h16[gm][c] = (bf16_t)hreg[j];
  }
  __syncthreads();

#pragma unroll 1
  for (int t = 0; t < TSTEPS; ++t) {
    // coalesced hs write: h16 currently holds h_t (t updates applied)
    if (t > 0) {
      const int m = tid >> 5, c0 = (tid & 31) * 8;
      bf16x8 v = *reinterpret_cast<const bf16x8*>(&h16[m][c0]);
      *reinterpret_cast<bf16x8*>(hs + ((size_t)(bw0 + m) * TSTEPS + (t - 1)) * EMB + c0) = v;
    }

    // gh = h @ W_hh^T (MFMA)
    f32x4 acc[6] = {};
#pragma unroll
    for (int kk = 0; kk < 8; ++kk) {
      bf16x8 a = *reinterpret_cast<const bf16x8*>(&h16[l15][kk * 32 + quad * 8]);
#pragma unroll
      for (int ct = 0; ct < 6; ++ct)
        acc[ct] = MFMA16(a, wfrag[ct][kk], acc[ct]);
    }
#pragma unroll
    for (int ct = 0; ct < 6; ++ct) {
      const int n = wv * 96 + ct * 16 + l15;
#pragma unroll
      for (int r = 0; r < 4; ++r) gh[quad * 4 + r][n] = acc[ct][r];
    }
    __syncthreads();

    // gates (fp32 master in hreg)
#pragma unroll
    for (int j = 0; j < 8; ++j) {
      const int c = gl + 32 * j;
      const float gr = gh[gm][c]       + bsum_r[c];
      const float gz = gh[gm][256 + c] + bsum_z[c];
      const float gn = gh[gm][512 + c] + bhhn_s[c];
      const float r  = 1.f / (1.f + __expf(-gr));
      const float z  = 1.f / (1.f + __expf(-gz));
      const float pre = bin_s[c] + r * gn;
      const float e2 = __expf(2.f * pre);
      const float nn = (e2 - 1.f) / (e2 + 1.f);
      hreg[j] = (1.f - z) * nn + z * hreg[j];
      h16[gm][c] = (bf16_t)hreg[j];
    }
    __syncthreads();
  }

  {  // final hs[127] = h_128
    const int m = tid >> 5, c0 = (tid & 31) * 8;
    bf16x8 v = *reinterpret_cast<const bf16x8*>(&h16[m][c0]);
    *reinterpret_cast<bf16x8*>(hs + ((size_t)(bw0 + m) * TSTEPS + 127) * EMB + c0) = v;
  }
}

// ---------------------------------------------------------------------------
// Fused MLP: 1024 WGs x 256 thr (4 waves), 64 rows/WG, one act buffer reused.
// Wave wv owns cols [wv*128,+128) as 8 col-tiles. Verified vs replica (R6).
// ---------------------------------------------------------------------------
template<int KC>
__device__ __forceinline__ void mlp_layer(
    const bf16_t* __restrict__ W, const float* __restrict__ bias,
    bf16_t (*act)[520], int wv, int l15, int quad)
{
  f32x4 acc[8][4] = {};
#pragma unroll 1
  for (int kc = 0; kc < KC; ++kc) {
    bf16x8 wf[8][4];
#pragma unroll
    for (int ct = 0; ct < 8; ++ct) {
      const bf16_t* wp = W + (size_t)(wv * 128 + ct * 16 + l15) * (KC * 128) + kc * 128 + quad * 8;
#pragma unroll
      for (int kk = 0; kk < 4; ++kk)
        wf[ct][kk] = *reinterpret_cast<const bf16x8*>(wp + kk * 32);
    }
#pragma unroll
    for (int mt = 0; mt < 4; ++mt) {
      bf16x8 a[4];
#pragma unroll
      for (int kk = 0; kk < 4; ++kk)
        a[kk] = *reinterpret_cast<const bf16x8*>(&act[mt * 16 + l15][kc * 128 + kk * 32 + quad * 8]);
#pragma unroll
      for (int kk = 0; kk < 4; ++kk)
#pragma unroll
        for (int ct = 0; ct < 8; ++ct)
          acc[ct][mt] = MFMA16(a[kk], wf[ct][kk], acc[ct][mt]);
    }
  }
  __syncthreads();   // all act reads done; safe to overwrite
#pragma unroll
  for (int ct = 0; ct < 8; ++ct) {
    const int n = wv * 128 + ct * 16 + l15;
    const float b = bias[n];
#pragma unroll
    for (int mt = 0; mt < 4; ++mt)
#pragma unroll
      for (int r = 0; r < 4; ++r) {
        float x = acc[ct][mt][r] + b;
        x = (x > 0.f) ? x : (__expf(x) - 1.f);   // ELU
        act[mt * 16 + quad * 4 + r][n] = (bf16_t)x;
      }
  }
  __syncthreads();
}

__global__ __launch_bounds__(256) void mlp_kernel(
    const bf16_t* __restrict__ hs,
    const bf16_t* __restrict__ w1, const float* __restrict__ b1,
    const bf16_t* __restrict__ w2, const float* __restrict__ b2,
    const bf16_t* __restrict__ w3, const float* __restrict__ b3,
    const bf16_t* __restrict__ muw, const float* __restrict__ mub,
    float* __restrict__ out)
{
  __shared__ __align__(16) bf16_t act[64][520];

  const int tid  = threadIdx.x;
  const int wv   = tid >> 6;
  const int lane = tid & 63;
  const int l15  = lane & 15;
  const int quad = lane >> 4;
  const int r0   = blockIdx.x * 64;

  for (int v = tid; v < 64 * 32; v += 256) {
    const int rr = v >> 5, cc = v & 31;
    bf16x8 x = *reinterpret_cast<const bf16x8*>(hs + (size_t)(r0 + rr) * EMB + cc * 8);
    *reinterpret_cast<bf16x8*>(&act[rr][cc * 8]) = x;
  }
  __syncthreads();

  mlp_layer<2>(w1, b1, act, wv, l15, quad);   // 256 -> 512
  mlp_layer<4>(w2, b2, act, wv, l15, quad);   // 512 -> 512
  mlp_layer<4>(w3, b3, act, wv, l15, quad);   // 512 -> 512

  // mu head: wave wv owns cols wv*16..+16
  f32x4 macc[4] = {};
  const int n = wv * 16 + l15;
#pragma unroll 1
  for (int kc = 0; kc < 4; ++kc) {
    bf16x8 wf[4];
#pragma unroll
    for (int kk = 0; kk < 4; ++kk)
      wf[kk] = *reinterpret_cast<const bf16x8*>(muw + (size_t)n * 512 + kc * 128 + kk * 32 + quad * 8);
#pragma unroll
    for (int mt = 0; mt < 4; ++mt)
#pragma unroll
      for (int kk = 0; kk < 4; ++kk) {
        bf16x8 a = *reinterpret_cast<const bf16x8*>(&act[mt * 16 + l15][kc * 128 + kk * 32 + quad * 8]);
        macc[mt] = MFMA16(a, wf[kk], macc[mt]);
      }
  }
  const float mb = mub[n];
#pragma unroll
  for (int mt = 0; mt < 4; ++mt)
#pragma unroll
    for (int r = 0; r < 4; ++r)
      out[(size_t)(r0 + mt * 16 + quad * 4 + r) * OUTD + n] = macc[mt][r] + mb;  // FP32
}

// ---------------------------------------------------------------------------
extern "C" void kernel_launch(void* const* d_in, const int* in_sizes, int n_in,
                              void* d_out, int out_size, void* d_ws, size_t ws_size,
                              hipStream_t stream) {
  char* ws = (char*)d_ws;

  convert_kernel<<<256, 256, 0, stream>>>(
      (const float*)d_in[3], (const float*)d_in[6], (const float*)d_in[8],
      (const float*)d_in[10], (const float*)d_in[12], ws);

  emb_kernel<<<512, 256, 0, stream>>>(
      (const float*)d_in[0], (const float*)d_in[1], (const float*)d_in[2],
      (float*)(ws + H0_OFF));

  gru_kernel<<<32, 512, 0, stream>>>(
      (const float*)(ws + H0_OFF), (const bf16_t*)(ws + WHH_OFF),
      (const float*)d_in[4], (const float*)d_in[5],
      (bf16_t*)(ws + HS_OFF));

  mlp_kernel<<<1024, 256, 0, stream>>>(
      (const bf16_t*)(ws + HS_OFF),
      (const bf16_t*)(ws + W1_OFF), (const float*)d_in[7],
      (const bf16_t*)(ws + W2_OFF), (const float*)d_in[9],
      (const bf16_t*)(ws + W3_OFF), (const float*)d_in[11],
      (const bf16_t*)(ws + MUW_OFF), (const float*)d_in[13],
      (float*)d_out);
}

// Round 18
// 414.359 us; speedup vs baseline: 91.1220x; 1.6450x over previous
//
#include <hip/hip_runtime.h>
#include <hip/hip_bf16.h>

// R18: GRU restructured to 1 barrier/step with in-register gates (wave owns
// cols c in [wv*32,+32) for ALL three gates -> gate inputs live in own accs;
// h16 double-buffered bf16 in LDS; biases in registers; v_rcp instead of
// divides). MLP: 512thr/8waves/128rows per WG (512 WGs) halves L2 weight
// traffic and doubles per-load MFMA amortization.

typedef __bf16 bf16_t;
typedef __bf16 bf16x8 __attribute__((ext_vector_type(8)));
typedef float f32x4 __attribute__((ext_vector_type(4)));

#define MFMA16(a, b, c) __builtin_amdgcn_mfma_f32_16x16x32_bf16(a, b, c, 0, 0, 0)

#define EMB 256
#define TSTEPS 128
#define OUTD 64

#define HS_OFF   0u           // bf16 65536x256 = 33,554,432
#define H0_OFF   33554432u    // f32 512x256   = 524,288
#define WHH_OFF  34078720u    // bf16 768x256  = 393,216
#define W1_OFF   34471936u    // bf16 512x256  = 262,144
#define W2_OFF   34734080u    // bf16 512x512  = 524,288
#define W3_OFF   35258368u    // bf16 512x512  = 524,288
#define MUW_OFF  35782656u    // bf16 64x512   = 65,536

__device__ __forceinline__ float rcpf(float x){ return __builtin_amdgcn_rcpf(x); }

// ---------------------------------------------------------------------------
__global__ __launch_bounds__(256) void convert_kernel(
    const float* __restrict__ whh, const float* __restrict__ w1,
    const float* __restrict__ w2, const float* __restrict__ w3,
    const float* __restrict__ muw, char* __restrict__ ws)
{
  const int g = blockIdx.x * 256 + threadIdx.x;
  const int G = gridDim.x * 256;
  bf16_t* d;
  d = (bf16_t*)(ws + WHH_OFF); for (int i = g; i < 196608; i += G) d[i] = (bf16_t)whh[i];
  d = (bf16_t*)(ws + W1_OFF);  for (int i = g; i < 131072; i += G) d[i] = (bf16_t)w1[i];
  d = (bf16_t*)(ws + W2_OFF);  for (int i = g; i < 262144; i += G) d[i] = (bf16_t)w2[i];
  d = (bf16_t*)(ws + W3_OFF);  for (int i = g; i < 262144; i += G) d[i] = (bf16_t)w3[i];
  d = (bf16_t*)(ws + MUW_OFF); for (int i = g; i < 32768;  i += G) d[i] = (bf16_t)muw[i];
}

// ---------------------------------------------------------------------------
__global__ __launch_bounds__(256) void emb_kernel(
    const float* __restrict__ z_t, const float* __restrict__ z_g,
    const float* __restrict__ w_emb, float* __restrict__ h0)
{
  __shared__ float zrow[128];
  const int bw = blockIdx.x, tid = threadIdx.x;
  if (tid < 128)
    zrow[tid] = (tid < 64) ? z_t[bw * 64 + tid] : z_g[(bw >> 4) * 64 + (tid - 64)];
  __syncthreads();
  const float4* wp = reinterpret_cast<const float4*>(w_emb + (size_t)tid * 128);
  float s = 0.f;
#pragma unroll
  for (int k4 = 0; k4 < 32; ++k4) {
    const float4 w = wp[k4];
    s += zrow[k4 * 4 + 0] * w.x + zrow[k4 * 4 + 1] * w.y
       + zrow[k4 * 4 + 2] * w.z + zrow[k4 * 4 + 3] * w.w;
  }
  h0[(size_t)bw * 256 + tid] = s;
}

// ---------------------------------------------------------------------------
// GRU: 32 WGs x 512 thr (8 waves), 16 rows/WG, 1 barrier/step.
// Wave wv owns h-cols [wv*32,+32): B-tiles ct = gate*2+cc at n = gate*256 +
// wv*32 + cc*16 + l15. Gates fully in-register (acc + hm + bias regs).
// h16 double-buffered bf16 LDS for MFMA A-reads + coalesced hs writes.
// ---------------------------------------------------------------------------
__global__ __launch_bounds__(512) void gru_kernel(
    const float* __restrict__ h0, const bf16_t* __restrict__ w_hh,
    const float* __restrict__ b_ih, const float* __restrict__ b_hh,
    bf16_t* __restrict__ hs)
{
  __shared__ __align__(16) bf16_t h16[2][16][264];

  const int tid  = threadIdx.x;
  const int wv   = tid >> 6;
  const int lane = tid & 63;
  const int l15  = lane & 15;
  const int quad = lane >> 4;
  const int bw0  = blockIdx.x * 16;

  // register-resident W_hh B-fragments
  bf16x8 wfrag[6][8];
#pragma unroll
  for (int ct = 0; ct < 6; ++ct) {
    const int n = (ct >> 1) * 256 + wv * 32 + (ct & 1) * 16 + l15;
#pragma unroll
    for (int kk = 0; kk < 8; ++kk)
      wfrag[ct][kk] = *reinterpret_cast<const bf16x8*>(w_hh + (size_t)n * 256 + kk * 32 + quad * 8);
  }

  // per-lane biases for owned cols c[cc] = wv*32 + cc*16 + l15
  float br[2], bz[2], bin[2], bhn[2];
#pragma unroll
  for (int cc = 0; cc < 2; ++cc) {
    const int c = wv * 32 + cc * 16 + l15;
    br[cc]  = b_ih[c]       + b_hh[c];
    bz[cc]  = b_ih[256 + c] + b_hh[256 + c];
    bin[cc] = b_ih[512 + c];
    bhn[cc] = b_hh[512 + c];
  }

  // fp32 h master: rows quad*4+r, cols c[cc]
  float hm[4][2];
#pragma unroll
  for (int r = 0; r < 4; ++r)
#pragma unroll
    for (int cc = 0; cc < 2; ++cc) {
      const int row = quad * 4 + r, c = wv * 32 + cc * 16 + l15;
      hm[r][cc] = h0[(size_t)(bw0 + row) * 256 + c];
      h16[0][row][c] = (bf16_t)hm[r][cc];
    }
  __syncthreads();

#pragma unroll 1
  for (int t = 0; t < TSTEPS; ++t) {
    const int cur = t & 1, nxt = cur ^ 1;

    // coalesced hs[t-1] write (h16[cur] holds h_t)
    if (t > 0) {
      const int m = tid >> 5, c0 = (tid & 31) * 8;
      bf16x8 v = *reinterpret_cast<const bf16x8*>(&h16[cur][m][c0]);
      *reinterpret_cast<bf16x8*>(hs + ((size_t)(bw0 + m) * TSTEPS + (t - 1)) * EMB + c0) = v;
    }

    // gh tiles for owned cols (in-register accumulators)
    f32x4 acc[6] = {};
#pragma unroll
    for (int kk = 0; kk < 8; ++kk) {
      bf16x8 a = *reinterpret_cast<const bf16x8*>(&h16[cur][l15][kk * 32 + quad * 8]);
#pragma unroll
      for (int ct = 0; ct < 6; ++ct)
        acc[ct] = MFMA16(a, wfrag[ct][kk], acc[ct]);
    }

    // gates fully in-register; write new h to h16[nxt]
#pragma unroll
    for (int cc = 0; cc < 2; ++cc) {
      const int c = wv * 32 + cc * 16 + l15;
#pragma unroll
      for (int r = 0; r < 4; ++r) {
        const float gr = acc[cc][r]     + br[cc];
        const float gz = acc[2 + cc][r] + bz[cc];
        const float gn = acc[4 + cc][r] + bhn[cc];
        const float rr = rcpf(1.f + __expf(-gr));
        const float zz = rcpf(1.f + __expf(-gz));
        const float pre = bin[cc] + rr * gn;
        const float nn = 1.f - 2.f * rcpf(__expf(2.f * pre) + 1.f);
        hm[r][cc] = (1.f - zz) * nn + zz * hm[r][cc];
        h16[nxt][quad * 4 + r][c] = (bf16_t)hm[r][cc];
      }
    }
    __syncthreads();
  }

  {  // final hs[127] = h_128 (in h16[0] after 128 steps)
    const int m = tid >> 5, c0 = (tid & 31) * 8;
    bf16x8 v = *reinterpret_cast<const bf16x8*>(&h16[0][m][c0]);
    *reinterpret_cast<bf16x8*>(hs + ((size_t)(bw0 + m) * TSTEPS + 127) * EMB + c0) = v;
  }
}

// ---------------------------------------------------------------------------
// Fused MLP: 512 WGs x 512 thr (8 waves), 128 rows/WG. Wave wv owns cols
// [wv*64,+64) (4 col-tiles); 8 m-tiles. Weight frags reloaded per kk (VGPR
// budget); act buffer reused across layers.
// ---------------------------------------------------------------------------
template<int KC>
__device__ __forceinline__ void mlp_layer(
    const bf16_t* __restrict__ W, const float* __restrict__ bias,
    bf16_t (*act)[520], int wv, int l15, int quad)
{
  f32x4 acc[4][8] = {};
#pragma unroll 1
  for (int kc = 0; kc < KC; ++kc) {
#pragma unroll
    for (int kk = 0; kk < 4; ++kk) {
      bf16x8 wf[4];
#pragma unroll
      for (int ct = 0; ct < 4; ++ct)
        wf[ct] = *reinterpret_cast<const bf16x8*>(
            W + (size_t)(wv * 64 + ct * 16 + l15) * (KC * 128) + kc * 128 + kk * 32 + quad * 8);
#pragma unroll
      for (int mt = 0; mt < 8; ++mt) {
        bf16x8 a = *reinterpret_cast<const bf16x8*>(&act[mt * 16 + l15][kc * 128 + kk * 32 + quad * 8]);
#pragma unroll
        for (int ct = 0; ct < 4; ++ct)
          acc[ct][mt] = MFMA16(a, wf[ct], acc[ct][mt]);
      }
    }
  }
  __syncthreads();   // all act reads done; safe to overwrite
#pragma unroll
  for (int ct = 0; ct < 4; ++ct) {
    const int n = wv * 64 + ct * 16 + l15;
    const float b = bias[n];
#pragma unroll
    for (int mt = 0; mt < 8; ++mt)
#pragma unroll
      for (int r = 0; r < 4; ++r) {
        float x = acc[ct][mt][r] + b;
        x = (x > 0.f) ? x : (__expf(x) - 1.f);   // ELU
        act[mt * 16 + quad * 4 + r][n] = (bf16_t)x;
      }
  }
  __syncthreads();
}

__global__ __launch_bounds__(512, 2) void mlp_kernel(
    const bf16_t* __restrict__ hs,
    const bf16_t* __restrict__ w1, const float* __restrict__ b1,
    const bf16_t* __restrict__ w2, const float* __restrict__ b2,
    const bf16_t* __restrict__ w3, const float* __restrict__ b3,
    const bf16_t* __restrict__ muw, const float* __restrict__ mub,
    float* __restrict__ out)
{
  __shared__ __align__(16) bf16_t act[128][520];   // 133,120 B

  const int tid  = threadIdx.x;
  const int wv   = tid >> 6;
  const int lane = tid & 63;
  const int l15  = lane & 15;
  const int quad = lane >> 4;
  const size_t r0 = (size_t)blockIdx.x * 128;

  for (int v = tid; v < 128 * 32; v += 512) {
    const int rr = v >> 5, cc = v & 31;
    bf16x8 x = *reinterpret_cast<const bf16x8*>(hs + (r0 + rr) * EMB + cc * 8);
    *reinterpret_cast<bf16x8*>(&act[rr][cc * 8]) = x;
  }
  __syncthreads();

  mlp_layer<2>(w1, b1, act, wv, l15, quad);   // 256 -> 512
  mlp_layer<4>(w2, b2, act, wv, l15, quad);   // 512 -> 512
  mlp_layer<4>(w3, b3, act, wv, l15, quad);   // 512 -> 512

  // mu head: wave wv -> col-tile (wv&3), m-tiles (wv>>2)*4 .. +4
  f32x4 macc[4] = {};
  const int n   = (wv & 3) * 16 + l15;
  const int mtb = (wv >> 2) * 4;
#pragma unroll 1
  for (int kc = 0; kc < 4; ++kc) {
#pragma unroll
    for (int kk = 0; kk < 4; ++kk) {
      bf16x8 wf = *reinterpret_cast<const bf16x8*>(
          muw + (size_t)n * 512 + kc * 128 + kk * 32 + quad * 8);
#pragma unroll
      for (int i = 0; i < 4; ++i) {
        bf16x8 a = *reinterpret_cast<const bf16x8*>(
            &act[(mtb + i) * 16 + l15][kc * 128 + kk * 32 + quad * 8]);
        macc[i] = MFMA16(a, wf, macc[i]);
      }
    }
  }
  const float mb = mub[n];
#pragma unroll
  for (int i = 0; i < 4; ++i)
#pragma unroll
    for (int r = 0; r < 4; ++r)
      out[(r0 + (mtb + i) * 16 + quad * 4 + r) * OUTD + n] = macc[i][r] + mb;
}

// ---------------------------------------------------------------------------
extern "C" void kernel_launch(void* const* d_in, const int* in_sizes, int n_in,
                              void* d_out, int out_size, void* d_ws, size_t ws_size,
                              hipStream_t stream) {
  char* ws = (char*)d_ws;

  convert_kernel<<<256, 256, 0, stream>>>(
      (const float*)d_in[3], (const float*)d_in[6], (const float*)d_in[8],
      (const float*)d_in[10], (const float*)d_in[12], ws);

  emb_kernel<<<512, 256, 0, stream>>>(
      (const float*)d_in[0], (const float*)d_in[1], (const float*)d_in[2],
      (float*)(ws + H0_OFF));

  gru_kernel<<<32, 512, 0, stream>>>(
      (const float*)(ws + H0_OFF), (const bf16_t*)(ws + WHH_OFF),
      (const float*)d_in[4], (const float*)d_in[5],
      (bf16_t*)(ws + HS_OFF));

  mlp_kernel<<<512, 512, 0, stream>>>(
      (const bf16_t*)(ws + HS_OFF),
      (const bf16_t*)(ws + W1_OFF), (const float*)d_in[7],
      (const bf16_t*)(ws + W2_OFF), (const float*)d_in[9],
      (const bf16_t*)(ws + W3_OFF), (const float*)d_in[11],
      (const bf16_t*)(ws + MUW_OFF), (const float*)d_in[13],
      (float*)d_out);
}